// Round 1
// baseline (2940.548 us; speedup 1.0000x reference)
//
#include <hip/hip_runtime.h>

#define N_NODES 100000
#define N_EDGES 600000
#define IN_C 128
#define HID_C 128
#define OUT_C 64

// ---------------------------------------------------------------------------
// Count in-degree per destination node, per relation.
__global__ void count_kernel(const int* __restrict__ e0, const int* __restrict__ e1,
                             const int* __restrict__ e2, int* __restrict__ cnt) {
    int e = blockIdx.x * blockDim.x + threadIdx.x;
    if (e >= N_EDGES) return;
    int r = blockIdx.y;
    const int* ei = (r == 0) ? e0 : (r == 1 ? e1 : e2);
    int dst = ei[N_EDGES + e];
    atomicAdd(&cnt[r * N_NODES + dst], 1);
}

// ---------------------------------------------------------------------------
// Scatter-add feat[src] rows (128 floats) into agg[dst]. One wave per edge,
// float2 per lane (64 lanes * 2 = 128 channels).
__global__ void scatter_kernel(const float* __restrict__ feat, const int* __restrict__ ei,
                               float* __restrict__ agg) {
    int wave = (blockIdx.x * blockDim.x + threadIdx.x) >> 6;
    int lane = threadIdx.x & 63;
    if (wave >= N_EDGES) return;
    int s = ei[wave];
    int d = ei[N_EDGES + wave];
    const float2 v = *(const float2*)(feat + (size_t)s * 128 + lane * 2);
    float* dsta = agg + (size_t)d * 128 + lane * 2;
    atomicAdd(dsta, v.x);
    atomicAdd(dsta + 1, v.y);
}

// ---------------------------------------------------------------------------
// Layer-1 fused GEMM: h (+)= relu((agg/cnt) @ Wl + bl + x @ Wr) / 3
// Block = 256 threads, tile = 32 nodes x 128 cols. Each thread: 16 nodes, 1 col.
__global__ __launch_bounds__(256) void gemm1_kernel(
    const float* __restrict__ agg, const int* __restrict__ cnt,
    const float* __restrict__ x, const float* __restrict__ Wl,
    const float* __restrict__ bl, const float* __restrict__ Wr,
    float* __restrict__ h, int first) {
    __shared__ float s_a[32 * 128];
    __shared__ float s_x[32 * 128];
    __shared__ float s_inv[32];
    int tid = threadIdx.x;
    int nbase = blockIdx.x * 32;
    for (int idx = tid; idx < 32 * 128; idx += 256) {
        int row = idx >> 7, k = idx & 127;
        size_t g = (size_t)(nbase + row) * 128 + k;
        s_x[idx] = x[g];
        s_a[idx] = agg[g];
    }
    if (tid < 32) s_inv[tid] = 1.0f / fmaxf((float)cnt[nbase + tid], 1.0f);
    __syncthreads();

    int c = tid & 127;
    int half = tid >> 7;               // 0 or 1: which 16-node group
    float accA[16], accB[16];
#pragma unroll
    for (int i = 0; i < 16; i++) { accA[i] = 0.f; accB[i] = 0.f; }
    const float* sa = s_a + half * 16 * 128;
    const float* sx = s_x + half * 16 * 128;
    for (int k = 0; k < 128; k++) {
        float wl = Wl[k * 128 + c];    // coalesced across lanes, L1/L2-hot
        float wr = Wr[k * 128 + c];
#pragma unroll
        for (int i = 0; i < 16; i++) {
            accA[i] = fmaf(sa[i * 128 + k], wl, accA[i]);  // LDS broadcast
            accB[i] = fmaf(sx[i * 128 + k], wr, accB[i]);
        }
    }
    float b = bl[c];
#pragma unroll
    for (int i = 0; i < 16; i++) {
        int row = half * 16 + i;
        float xi = accA[i] * s_inv[row] + b + accB[i];
        float v = fmaxf(xi, 0.f) * (1.0f / 3.0f);
        size_t o = (size_t)(nbase + row) * 128 + c;
        if (first) h[o] = v; else h[o] += v;
    }
}

// ---------------------------------------------------------------------------
// Layer-2 GEMM: out = (aggf/cnt0) @ Wl_f + bl_f + h @ Wr_f   (64 cols, no relu)
__global__ __launch_bounds__(256) void gemm2_kernel(
    const float* __restrict__ agg, const int* __restrict__ cnt,
    const float* __restrict__ hh, const float* __restrict__ Wl,
    const float* __restrict__ bl, const float* __restrict__ Wr,
    float* __restrict__ out) {
    __shared__ float s_a[32 * 128];
    __shared__ float s_h[32 * 128];
    __shared__ float s_inv[32];
    int tid = threadIdx.x;
    int nbase = blockIdx.x * 32;
    for (int idx = tid; idx < 32 * 128; idx += 256) {
        int row = idx >> 7, k = idx & 127;
        size_t g = (size_t)(nbase + row) * 128 + k;
        s_h[idx] = hh[g];
        s_a[idx] = agg[g];
    }
    if (tid < 32) s_inv[tid] = 1.0f / fmaxf((float)cnt[nbase + tid], 1.0f);
    __syncthreads();

    int c = tid & 63;
    int part = tid >> 6;               // 0..3: which 8-node group
    float accA[8], accB[8];
#pragma unroll
    for (int i = 0; i < 8; i++) { accA[i] = 0.f; accB[i] = 0.f; }
    const float* sa = s_a + part * 8 * 128;
    const float* sh = s_h + part * 8 * 128;
    for (int k = 0; k < 128; k++) {
        float wl = Wl[k * 64 + c];
        float wr = Wr[k * 64 + c];
#pragma unroll
        for (int i = 0; i < 8; i++) {
            accA[i] = fmaf(sa[i * 128 + k], wl, accA[i]);
            accB[i] = fmaf(sh[i * 128 + k], wr, accB[i]);
        }
    }
    float b = bl[c];
#pragma unroll
    for (int i = 0; i < 8; i++) {
        int row = part * 8 + i;
        out[(size_t)(nbase + row) * 64 + c] = accA[i] * s_inv[row] + b + accB[i];
    }
}

// ---------------------------------------------------------------------------
extern "C" void kernel_launch(void* const* d_in, const int* in_sizes, int n_in,
                              void* d_out, int out_size, void* d_ws, size_t ws_size,
                              hipStream_t stream) {
    const float* x    = (const float*)d_in[0];
    const float* Wl   = (const float*)d_in[1];
    const float* bl   = (const float*)d_in[2];
    const float* Wr   = (const float*)d_in[3];
    const float* Wl_f = (const float*)d_in[4];
    const float* bl_f = (const float*)d_in[5];
    const float* Wr_f = (const float*)d_in[6];
    const int* ei0 = (const int*)d_in[7];
    const int* ei1 = (const int*)d_in[8];
    const int* ei2 = (const int*)d_in[9];
    const int* eis[3] = {ei0, ei1, ei2};
    float* out = (float*)d_out;

    // workspace layout: cnt[3*N] ints @0, agg[N*128] @2MB, h[N*128] after agg
    char* ws = (char*)d_ws;
    int* cnt   = (int*)ws;
    float* agg = (float*)(ws + (size_t)(2u << 20));
    float* h   = (float*)(ws + (size_t)(2u << 20) + (size_t)N_NODES * 128 * sizeof(float));

    hipMemsetAsync(cnt, 0, 3 * N_NODES * sizeof(int), stream);
    {
        dim3 g((N_EDGES + 255) / 256, 3);
        count_kernel<<<g, 256, 0, stream>>>(ei0, ei1, ei2, cnt);
    }

    for (int r = 0; r < 3; r++) {
        hipMemsetAsync(agg, 0, (size_t)N_NODES * 128 * sizeof(float), stream);
        scatter_kernel<<<N_EDGES / 4, 256, 0, stream>>>(x, eis[r], agg);
        gemm1_kernel<<<N_NODES / 32, 256, 0, stream>>>(
            agg, cnt + r * N_NODES, x,
            Wl + (size_t)r * IN_C * HID_C, bl + r * HID_C,
            Wr + (size_t)r * IN_C * HID_C, h, r == 0 ? 1 : 0);
    }

    // final layer: same edge list / counts as relation 0, on h
    hipMemsetAsync(agg, 0, (size_t)N_NODES * 128 * sizeof(float), stream);
    scatter_kernel<<<N_EDGES / 4, 256, 0, stream>>>(h, ei0, agg);
    gemm2_kernel<<<N_NODES / 32, 256, 0, stream>>>(agg, cnt, h, Wl_f, bl_f, Wr_f, out);
}

// Round 2
// 1375.717 us; speedup vs baseline: 2.1375x; 2.1375x over previous
//
#include <hip/hip_runtime.h>

#define N_NODES 100000
#define N_EDGES 600000
#define IN_C 128
#define HID_C 128
#define OUT_C 64

// ---------------------------------------------------------------------------
// In-degree per destination node, per relation (int atomics, cheap).
__global__ void count_kernel(const int* __restrict__ e0, const int* __restrict__ e1,
                             const int* __restrict__ e2, int* __restrict__ cnt) {
    int e = blockIdx.x * blockDim.x + threadIdx.x;
    if (e >= N_EDGES) return;
    int r = blockIdx.y;
    const int* ei = (r == 0) ? e0 : (r == 1 ? e1 : e2);
    atomicAdd(&cnt[r * N_NODES + ei[N_EDGES + e]], 1);
}

// ---------------------------------------------------------------------------
// Exclusive prefix sum of cnt -> rowstart. One 1024-thread block per relation.
// Wave-level shfl scan + LDS wave-sum scan (3 barriers per 1024-chunk).
__global__ __launch_bounds__(1024) void scan_kernel(const int* __restrict__ cnt,
                                                    int* __restrict__ rowstart) {
    int r = blockIdx.x;
    const int* c = cnt + r * N_NODES;
    int* rs = rowstart + r * N_NODES;
    __shared__ int wsum[16];
    __shared__ int s_carry;
    int tid = threadIdx.x, lane = tid & 63, wid = tid >> 6;
    if (tid == 0) s_carry = 0;
    __syncthreads();
    for (int base = 0; base < N_NODES; base += 1024) {
        int i = base + tid;
        int v = (i < N_NODES) ? c[i] : 0;
        int incl = v;
#pragma unroll
        for (int off = 1; off < 64; off <<= 1) {
            int t = __shfl_up(incl, off);
            if (lane >= off) incl += t;
        }
        if (lane == 63) wsum[wid] = incl;
        __syncthreads();
        if (wid == 0) {
            int wv = (lane < 16) ? wsum[lane] : 0;
#pragma unroll
            for (int off = 1; off < 16; off <<= 1) {
                int t = __shfl_up(wv, off);
                if (lane >= off) wv += t;
            }
            if (lane < 16) wsum[lane] = wv;
        }
        __syncthreads();
        int carry = s_carry;
        int woff = (wid > 0) ? wsum[wid - 1] : 0;
        if (i < N_NODES) rs[i] = carry + woff + (incl - v);
        __syncthreads();
        if (tid == 0) s_carry = carry + wsum[15];
        __syncthreads();
    }
}

// ---------------------------------------------------------------------------
// CSR fill: place each edge's src into adj at rowstart[dst] + cursor++.
__global__ void fill_kernel(const int* __restrict__ e0, const int* __restrict__ e1,
                            const int* __restrict__ e2, const int* __restrict__ rowstart,
                            int* __restrict__ cursor, int* __restrict__ adj) {
    int e = blockIdx.x * blockDim.x + threadIdx.x;
    if (e >= N_EDGES) return;
    int r = blockIdx.y;
    const int* ei = (r == 0) ? e0 : (r == 1 ? e1 : e2);
    int src = ei[e], dst = ei[N_EDGES + e];
    int pos = atomicAdd(&cursor[r * N_NODES + dst], 1);
    adj[(size_t)r * N_EDGES + rowstart[r * N_NODES + dst] + pos] = src;
}

// ---------------------------------------------------------------------------
// Gather-mean, 128 channels: one wave per node, float2 per lane.
__global__ void gather128_kernel(const float* __restrict__ feat, const int* __restrict__ adj,
                                 const int* __restrict__ rowstart, const int* __restrict__ cnt,
                                 float* __restrict__ agg) {
    int node = (blockIdx.x * blockDim.x + threadIdx.x) >> 6;
    int lane = threadIdx.x & 63;
    if (node >= N_NODES) return;
    int start = rowstart[node];
    int deg = cnt[node];
    float ax = 0.f, ay = 0.f;
    for (int j = 0; j < deg; j++) {
        int s = adj[start + j];                       // wave-uniform broadcast
        const float2 v = *(const float2*)(feat + (size_t)s * 128 + lane * 2);
        ax += v.x; ay += v.y;
    }
    float inv = 1.0f / fmaxf((float)deg, 1.0f);
    *(float2*)(agg + (size_t)node * 128 + lane * 2) = make_float2(ax * inv, ay * inv);
}

// ---------------------------------------------------------------------------
// Gather-mean, 64 channels: one wave per node, 1 float per lane.
__global__ void gather64_kernel(const float* __restrict__ feat, const int* __restrict__ adj,
                                const int* __restrict__ rowstart, const int* __restrict__ cnt,
                                float* __restrict__ agg) {
    int node = (blockIdx.x * blockDim.x + threadIdx.x) >> 6;
    int lane = threadIdx.x & 63;
    if (node >= N_NODES) return;
    int start = rowstart[node];
    int deg = cnt[node];
    float a = 0.f;
    for (int j = 0; j < deg; j++) {
        int s = adj[start + j];
        a += feat[(size_t)s * 64 + lane];
    }
    agg[(size_t)node * 64 + lane] = a / fmaxf((float)deg, 1.0f);
}

// ---------------------------------------------------------------------------
// Layer-1 fused GEMM: h (+)= relu(agg @ Wl + bl + x @ Wr) / 3  (agg pre-divided)
__global__ __launch_bounds__(256) void gemm1_kernel(
    const float* __restrict__ agg, const float* __restrict__ x,
    const float* __restrict__ Wl, const float* __restrict__ bl,
    const float* __restrict__ Wr, float* __restrict__ h, int first) {
    __shared__ float s_a[32 * 128];
    __shared__ float s_x[32 * 128];
    int tid = threadIdx.x;
    int nbase = blockIdx.x * 32;
    for (int idx = tid; idx < 32 * 128; idx += 256) {
        size_t g = (size_t)nbase * 128 + idx;
        s_x[idx] = x[g];
        s_a[idx] = agg[g];
    }
    __syncthreads();

    int c = tid & 127;
    int half = tid >> 7;
    float accA[16], accB[16];
#pragma unroll
    for (int i = 0; i < 16; i++) { accA[i] = 0.f; accB[i] = 0.f; }
    const float* sa = s_a + half * 16 * 128;
    const float* sx = s_x + half * 16 * 128;
    for (int k = 0; k < 128; k++) {
        float wl = Wl[k * 128 + c];
        float wr = Wr[k * 128 + c];
#pragma unroll
        for (int i = 0; i < 16; i++) {
            accA[i] = fmaf(sa[i * 128 + k], wl, accA[i]);
            accB[i] = fmaf(sx[i * 128 + k], wr, accB[i]);
        }
    }
    float b = bl[c];
#pragma unroll
    for (int i = 0; i < 16; i++) {
        int row = half * 16 + i;
        float v = fmaxf(accA[i] + b + accB[i], 0.f) * (1.0f / 3.0f);
        size_t o = (size_t)(nbase + row) * 128 + c;
        if (first) h[o] = v; else h[o] += v;
    }
}

// ---------------------------------------------------------------------------
// hWl = h @ Wl_f  (100k x 128 @ 128 x 64)
__global__ __launch_bounds__(256) void gemm2a_kernel(
    const float* __restrict__ h, const float* __restrict__ Wl, float* __restrict__ hWl) {
    __shared__ float s_h[32 * 128];
    int tid = threadIdx.x;
    int nbase = blockIdx.x * 32;
    for (int idx = tid; idx < 32 * 128; idx += 256)
        s_h[idx] = h[(size_t)nbase * 128 + idx];
    __syncthreads();
    int c = tid & 63;
    int part = tid >> 6;
    float acc[8];
#pragma unroll
    for (int i = 0; i < 8; i++) acc[i] = 0.f;
    const float* sh = s_h + part * 8 * 128;
    for (int k = 0; k < 128; k++) {
        float wl = Wl[k * 64 + c];
#pragma unroll
        for (int i = 0; i < 8; i++) acc[i] = fmaf(sh[i * 128 + k], wl, acc[i]);
    }
#pragma unroll
    for (int i = 0; i < 8; i++)
        hWl[(size_t)(nbase + part * 8 + i) * 64 + c] = acc[i];
}

// ---------------------------------------------------------------------------
// out = aggf + bl_f + h @ Wr_f
__global__ __launch_bounds__(256) void gemm2b_kernel(
    const float* __restrict__ aggf, const float* __restrict__ h,
    const float* __restrict__ Wr, const float* __restrict__ bl, float* __restrict__ out) {
    __shared__ float s_h[32 * 128];
    int tid = threadIdx.x;
    int nbase = blockIdx.x * 32;
    for (int idx = tid; idx < 32 * 128; idx += 256)
        s_h[idx] = h[(size_t)nbase * 128 + idx];
    __syncthreads();
    int c = tid & 63;
    int part = tid >> 6;
    float acc[8];
#pragma unroll
    for (int i = 0; i < 8; i++) acc[i] = 0.f;
    const float* sh = s_h + part * 8 * 128;
    for (int k = 0; k < 128; k++) {
        float wr = Wr[k * 64 + c];
#pragma unroll
        for (int i = 0; i < 8; i++) acc[i] = fmaf(sh[i * 128 + k], wr, acc[i]);
    }
    float b = bl[c];
#pragma unroll
    for (int i = 0; i < 8; i++) {
        size_t o = (size_t)(nbase + part * 8 + i) * 64 + c;
        out[o] = aggf[o] + b + acc[i];
    }
}

// ---------------------------------------------------------------------------
extern "C" void kernel_launch(void* const* d_in, const int* in_sizes, int n_in,
                              void* d_out, int out_size, void* d_ws, size_t ws_size,
                              hipStream_t stream) {
    const float* x    = (const float*)d_in[0];
    const float* Wl   = (const float*)d_in[1];
    const float* bl   = (const float*)d_in[2];
    const float* Wr   = (const float*)d_in[3];
    const float* Wl_f = (const float*)d_in[4];
    const float* bl_f = (const float*)d_in[5];
    const float* Wr_f = (const float*)d_in[6];
    const int* ei0 = (const int*)d_in[7];
    const int* ei1 = (const int*)d_in[8];
    const int* ei2 = (const int*)d_in[9];
    float* out = (float*)d_out;

    // workspace layout (MB offsets)
    char* ws = (char*)d_ws;
    int* cnt      = (int*)(ws);                          // 1.2 MB
    int* cursor   = (int*)(ws + (size_t)(2u  << 20));    // 1.2 MB
    int* rowstart = (int*)(ws + (size_t)(4u  << 20));    // 1.2 MB
    int* adj      = (int*)(ws + (size_t)(6u  << 20));    // 7.2 MB (3 relations)
    float* agg    = (float*)(ws + (size_t)(16u << 20));  // 51.2 MB
    float* hWl    = (float*)(ws + (size_t)(16u << 20));  // reuses agg after layer 1
    float* aggf   = (float*)(ws + (size_t)(44u << 20));  // 25.6 MB
    float* h      = (float*)(ws + (size_t)(72u << 20));  // 51.2 MB

    hipMemsetAsync(cnt, 0, 3 * N_NODES * sizeof(int), stream);
    hipMemsetAsync(cursor, 0, 3 * N_NODES * sizeof(int), stream);

    dim3 ge((N_EDGES + 255) / 256, 3);
    count_kernel<<<ge, 256, 0, stream>>>(ei0, ei1, ei2, cnt);
    scan_kernel<<<3, 1024, 0, stream>>>(cnt, rowstart);
    fill_kernel<<<ge, 256, 0, stream>>>(ei0, ei1, ei2, rowstart, cursor, adj);

    const int GATHER_BLOCKS = (N_NODES * 64) / 256;  // 25000
    for (int r = 0; r < 3; r++) {
        gather128_kernel<<<GATHER_BLOCKS, 256, 0, stream>>>(
            x, adj + (size_t)r * N_EDGES, rowstart + r * N_NODES, cnt + r * N_NODES, agg);
        gemm1_kernel<<<N_NODES / 32, 256, 0, stream>>>(
            agg, x, Wl + (size_t)r * IN_C * HID_C, bl + r * HID_C,
            Wr + (size_t)r * IN_C * HID_C, h, r == 0 ? 1 : 0);
    }

    // final layer: premultiply (linearity: mean(h)@Wl_f == mean(h@Wl_f))
    gemm2a_kernel<<<N_NODES / 32, 256, 0, stream>>>(h, Wl_f, hWl);
    gather64_kernel<<<GATHER_BLOCKS, 256, 0, stream>>>(hWl, adj, rowstart, cnt, aggf);
    gemm2b_kernel<<<N_NODES / 32, 256, 0, stream>>>(aggf, h, Wr_f, bl_f, out);
}

// Round 3
// 707.944 us; speedup vs baseline: 4.1536x; 1.9433x over previous
//
#include <hip/hip_runtime.h>

#define N_NODES 100000
#define N_EDGES 600000
#define IN_C 128
#define HID_C 128
#define OUT_C 64
#define NCHUNK 98            // ceil(100000/1024)
#define NROWS2 100032        // N_NODES rounded up to 64
#define LDS_STRIDE 136       // ushorts per row: 128 + 8 pad (breaks bank aliasing)

typedef __attribute__((ext_vector_type(8))) short short8;
typedef __attribute__((ext_vector_type(4))) float f32x4;
typedef __attribute__((ext_vector_type(4))) unsigned short ushort4v;
typedef __attribute__((ext_vector_type(2))) unsigned short ushort2v;

__device__ __forceinline__ unsigned short f2b(float f) {   // fp32 -> bf16 RNE
    unsigned u = __builtin_bit_cast(unsigned, f);
    return (unsigned short)((u + 0x7fffu + ((u >> 16) & 1u)) >> 16);
}
__device__ __forceinline__ float b2f(unsigned short b) {
    return __builtin_bit_cast(float, (unsigned)b << 16);
}

// ---------------------------------------------------------------------------
__global__ void count_kernel(const int* __restrict__ e0, const int* __restrict__ e1,
                             const int* __restrict__ e2, int* __restrict__ cnt) {
    int e = blockIdx.x * blockDim.x + threadIdx.x;
    if (e >= N_EDGES) return;
    int r = blockIdx.y;
    const int* ei = (r == 0) ? e0 : (r == 1 ? e1 : e2);
    atomicAdd(&cnt[r * N_NODES + ei[N_EDGES + e]], 1);
}

// ---------------------------------------------------------------------------
// Two-phase exclusive scan. Phase 1: per-1024-block scan + block totals.
__global__ __launch_bounds__(1024) void scan1_kernel(const int* __restrict__ cnt,
                                                     int* __restrict__ rowstart,
                                                     int* __restrict__ blocksum) {
    int r = blockIdx.y;
    int tid = threadIdx.x, lane = tid & 63, wid = tid >> 6;
    int i = blockIdx.x * 1024 + tid;
    __shared__ int wsum[16];
    int v = (i < N_NODES) ? cnt[r * N_NODES + i] : 0;
    int incl = v;
#pragma unroll
    for (int off = 1; off < 64; off <<= 1) {
        int t = __shfl_up(incl, off);
        if (lane >= off) incl += t;
    }
    if (lane == 63) wsum[wid] = incl;
    __syncthreads();
    if (wid == 0) {
        int wv = (lane < 16) ? wsum[lane] : 0;
#pragma unroll
        for (int off = 1; off < 16; off <<= 1) {
            int t = __shfl_up(wv, off);
            if (lane >= off) wv += t;
        }
        if (lane < 16) wsum[lane] = wv;
    }
    __syncthreads();
    int woff = (wid > 0) ? wsum[wid - 1] : 0;
    if (i < N_NODES) rowstart[r * N_NODES + i] = woff + incl - v;
    if (tid == 0) blocksum[r * NCHUNK + blockIdx.x] = wsum[15];
}

// Phase 2: scan the 3x98 block totals (3 independent serial scans in LDS).
__global__ __launch_bounds__(128) void scan2_kernel(int* __restrict__ blocksum) {
    __shared__ int s[3 * NCHUNK];
    int tid = threadIdx.x;
    for (int i = tid; i < 3 * NCHUNK; i += 128) s[i] = blocksum[i];
    __syncthreads();
    if (tid < 3) {
        int run = 0;
        for (int j = 0; j < NCHUNK; j++) { int t = s[tid * NCHUNK + j]; s[tid * NCHUNK + j] = run; run += t; }
    }
    __syncthreads();
    for (int i = tid; i < 3 * NCHUNK; i += 128) blocksum[i] = s[i];
}

// Phase 3: add block offsets.
__global__ void scan3_kernel(int* __restrict__ rowstart, const int* __restrict__ blocksum) {
    int r = blockIdx.y;
    int i = blockIdx.x * 256 + threadIdx.x;
    if (i < N_NODES) rowstart[r * N_NODES + i] += blocksum[r * NCHUNK + (i >> 10)];
}

// ---------------------------------------------------------------------------
__global__ void fill_kernel(const int* __restrict__ e0, const int* __restrict__ e1,
                            const int* __restrict__ e2, const int* __restrict__ rowstart,
                            int* __restrict__ cursor, int* __restrict__ adj) {
    int e = blockIdx.x * blockDim.x + threadIdx.x;
    if (e >= N_EDGES) return;
    int r = blockIdx.y;
    const int* ei = (r == 0) ? e0 : (r == 1 ? e1 : e2);
    int src = ei[e], dst = ei[N_EDGES + e];
    int pos = atomicAdd(&cursor[r * N_NODES + dst], 1);
    adj[(size_t)r * N_EDGES + rowstart[r * N_NODES + dst] + pos] = src;
}

// ---------------------------------------------------------------------------
// Weight prep: WcatT[r][n][k] = (k<128 ? Wl[r][k][n] : Wr[r][k-128][n]) as bf16
//              Wcat2T[n][k]  = (n<64 ? Wl_f[k][n] : Wr_f[k][n-64])      as bf16
__global__ void wprep_kernel(const float* __restrict__ Wl, const float* __restrict__ Wr,
                             const float* __restrict__ Wl_f, const float* __restrict__ Wr_f,
                             unsigned short* __restrict__ WcatT, unsigned short* __restrict__ Wcat2T) {
    int idx = blockIdx.x * 256 + threadIdx.x;
    if (idx < 3 * 128 * 256) {
        int r = idx >> 15;
        int rem = idx & 32767;
        int n = rem >> 8, k = rem & 255;
        float v = (k < 128) ? Wl[((size_t)r * 128 + k) * 128 + n]
                            : Wr[((size_t)r * 128 + (k - 128)) * 128 + n];
        WcatT[idx] = f2b(v);
    } else {
        int i2 = idx - 3 * 128 * 256;
        if (i2 < 128 * 128) {
            int n = i2 >> 7, k = i2 & 127;
            float v = (n < 64) ? Wl_f[(size_t)k * 64 + n] : Wr_f[(size_t)k * 64 + (n - 64)];
            Wcat2T[i2] = f2b(v);
        }
    }
}

// ---------------------------------------------------------------------------
// Gather-mean, 128 ch fp32 input -> bf16 output. One wave/node, float2/lane.
__global__ void gather128_kernel(const float* __restrict__ feat, const int* __restrict__ adj,
                                 const int* __restrict__ rowstart, const int* __restrict__ cnt,
                                 unsigned short* __restrict__ aggb) {
    int node = (blockIdx.x * blockDim.x + threadIdx.x) >> 6;
    int lane = threadIdx.x & 63;
    if (node >= N_NODES) return;
    int start = rowstart[node];
    int deg = cnt[node];
    float ax = 0.f, ay = 0.f;
    int j = 0;
    for (; j + 4 <= deg; j += 4) {
        int s0 = adj[start + j], s1 = adj[start + j + 1];
        int s2 = adj[start + j + 2], s3 = adj[start + j + 3];
        float2 v0 = *(const float2*)(feat + (size_t)s0 * 128 + lane * 2);
        float2 v1 = *(const float2*)(feat + (size_t)s1 * 128 + lane * 2);
        float2 v2 = *(const float2*)(feat + (size_t)s2 * 128 + lane * 2);
        float2 v3 = *(const float2*)(feat + (size_t)s3 * 128 + lane * 2);
        ax += v0.x + v1.x + v2.x + v3.x;
        ay += v0.y + v1.y + v2.y + v3.y;
    }
    for (; j < deg; j++) {
        int s = adj[start + j];
        float2 v = *(const float2*)(feat + (size_t)s * 128 + lane * 2);
        ax += v.x; ay += v.y;
    }
    float inv = 1.0f / fmaxf((float)deg, 1.0f);
    ushort2v o; o.x = f2b(ax * inv); o.y = f2b(ay * inv);
    *(ushort2v*)(aggb + (size_t)node * 128 + lane * 2) = o;
}

// ---------------------------------------------------------------------------
// Fused: for r in 0..2: acc = [agg_r | x](K=256) @ WcatT_r; h += relu(acc+bl)/3
// then [hWl|hWr] = h @ Wcat2T (K=128); hWl->bf16 buffer, out = hWr + bl_f.
// Block = 256 thr (4 waves), tile = 64 rows x 128 cols, 16x16x32 bf16 MFMA.
__global__ __launch_bounds__(256) void mega_kernel(
    const unsigned short* __restrict__ aggb, const float* __restrict__ x,
    const unsigned short* __restrict__ WcatT, const float* __restrict__ bl,
    const unsigned short* __restrict__ Wcat2T, const float* __restrict__ bl_f,
    unsigned short* __restrict__ hWlb, float* __restrict__ out) {
    __shared__ unsigned short s_x[64 * LDS_STRIDE];
    __shared__ unsigned short s_a[64 * LDS_STRIDE];
    __shared__ unsigned short s_h[64 * LDS_STRIDE];
    int tid = threadIdx.x;
    int wave = tid >> 6, lane = tid & 63;
    int quad = lane >> 4, l16 = lane & 15;
    int rowbase = blockIdx.x * 64;

    // stage x tile (fp32 -> bf16): 64 rows x 32 float4 chunks
#pragma unroll
    for (int it = 0; it < 8; it++) {
        int idx = tid + it * 256;
        int row = idx >> 5, c = idx & 31;
        int grow = rowbase + row;
        float4 v = (grow < N_NODES) ? ((const float4*)x)[(size_t)grow * 32 + c]
                                    : make_float4(0.f, 0.f, 0.f, 0.f);
        ushort4v b; b.x = f2b(v.x); b.y = f2b(v.y); b.z = f2b(v.z); b.w = f2b(v.w);
        *(ushort4v*)&s_x[row * LDS_STRIDE + c * 4] = b;
    }

    float hacc[8][4];
#pragma unroll
    for (int t = 0; t < 8; t++)
#pragma unroll
        for (int q = 0; q < 4; q++) hacc[t][q] = 0.f;

    for (int r = 0; r < 3; r++) {
        __syncthreads();   // prior reads of s_a done (and covers s_x staging on r=0)
        const unsigned short* ag = aggb + (size_t)r * NROWS2 * 128;
#pragma unroll
        for (int it = 0; it < 4; it++) {
            int idx = tid + it * 256;
            int row = idx >> 4, c = idx & 15;
            short8 v = *(const short8*)(ag + (size_t)(rowbase + row) * 128 + c * 8);
            *(short8*)&s_a[row * LDS_STRIDE + c * 8] = v;
        }
        __syncthreads();

        f32x4 acc[8];
#pragma unroll
        for (int t = 0; t < 8; t++) acc[t] = (f32x4){0.f, 0.f, 0.f, 0.f};
        const unsigned short* W = WcatT + (size_t)r * 128 * 256;
#pragma unroll
        for (int s = 0; s < 8; s++) {
            const unsigned short* ab = (s < 4)
                ? &s_a[(wave * 16 + l16) * LDS_STRIDE + s * 32 + quad * 8]
                : &s_x[(wave * 16 + l16) * LDS_STRIDE + (s - 4) * 32 + quad * 8];
            short8 afrag = *(const short8*)ab;
#pragma unroll
            for (int t = 0; t < 8; t++) {
                short8 bfrag = *(const short8*)(W + (size_t)(t * 16 + l16) * 256 + s * 32 + quad * 8);
                acc[t] = __builtin_amdgcn_mfma_f32_16x16x32_bf16(afrag, bfrag, acc[t], 0, 0, 0);
            }
        }
#pragma unroll
        for (int t = 0; t < 8; t++) {
            float bb = bl[r * 128 + t * 16 + l16];
#pragma unroll
            for (int q = 0; q < 4; q++)
                hacc[t][q] += fmaxf(acc[t][q] + bb, 0.f) * (1.0f / 3.0f);
        }
    }

    // h (C-layout regs) -> LDS bf16 in A-layout
#pragma unroll
    for (int t = 0; t < 8; t++)
#pragma unroll
        for (int q = 0; q < 4; q++) {
            int row = wave * 16 + quad * 4 + q;
            s_h[row * LDS_STRIDE + t * 16 + l16] = f2b(hacc[t][q]);
        }
    __syncthreads();

    // layer 2: h @ Wcat2T (K=128)
    f32x4 acc2[8];
#pragma unroll
    for (int t = 0; t < 8; t++) acc2[t] = (f32x4){0.f, 0.f, 0.f, 0.f};
#pragma unroll
    for (int s = 0; s < 4; s++) {
        short8 afrag = *(const short8*)&s_h[(wave * 16 + l16) * LDS_STRIDE + s * 32 + quad * 8];
#pragma unroll
        for (int t = 0; t < 8; t++) {
            short8 bfrag = *(const short8*)(Wcat2T + (size_t)(t * 16 + l16) * 128 + s * 32 + quad * 8);
            acc2[t] = __builtin_amdgcn_mfma_f32_16x16x32_bf16(afrag, bfrag, acc2[t], 0, 0, 0);
        }
    }

    // epilogue: cols 0..63 -> hWlb (bf16), cols 64..127 -> out (+bl_f)
#pragma unroll
    for (int t = 0; t < 8; t++) {
        int col = t * 16 + l16;
#pragma unroll
        for (int q = 0; q < 4; q++) {
            int row = rowbase + wave * 16 + quad * 4 + q;
            if (row < N_NODES) {
                if (col < 64) hWlb[(size_t)row * 64 + col] = f2b(acc2[t][q]);
                else out[(size_t)row * 64 + (col - 64)] = acc2[t][q] + bl_f[col - 64];
            }
        }
    }
}

// ---------------------------------------------------------------------------
// Gather-mean of hWl (bf16, 64 ch) + add into out (which holds hWr + bl_f).
__global__ void gather64_kernel(const unsigned short* __restrict__ hWlb, const int* __restrict__ adj,
                                const int* __restrict__ rowstart, const int* __restrict__ cnt,
                                float* __restrict__ out) {
    int node = (blockIdx.x * blockDim.x + threadIdx.x) >> 6;
    int lane = threadIdx.x & 63;
    if (node >= N_NODES) return;
    int start = rowstart[node];
    int deg = cnt[node];
    float a = 0.f;
    int j = 0;
    for (; j + 4 <= deg; j += 4) {
        int s0 = adj[start + j], s1 = adj[start + j + 1];
        int s2 = adj[start + j + 2], s3 = adj[start + j + 3];
        a += b2f(hWlb[(size_t)s0 * 64 + lane]) + b2f(hWlb[(size_t)s1 * 64 + lane])
           + b2f(hWlb[(size_t)s2 * 64 + lane]) + b2f(hWlb[(size_t)s3 * 64 + lane]);
    }
    for (; j < deg; j++) a += b2f(hWlb[(size_t)adj[start + j] * 64 + lane]);
    out[(size_t)node * 64 + lane] += a / fmaxf((float)deg, 1.0f);
}

// ---------------------------------------------------------------------------
extern "C" void kernel_launch(void* const* d_in, const int* in_sizes, int n_in,
                              void* d_out, int out_size, void* d_ws, size_t ws_size,
                              hipStream_t stream) {
    const float* x    = (const float*)d_in[0];
    const float* Wl   = (const float*)d_in[1];
    const float* bl   = (const float*)d_in[2];
    const float* Wr   = (const float*)d_in[3];
    const float* Wl_f = (const float*)d_in[4];
    const float* bl_f = (const float*)d_in[5];
    const float* Wr_f = (const float*)d_in[6];
    const int* ei0 = (const int*)d_in[7];
    const int* ei1 = (const int*)d_in[8];
    const int* ei2 = (const int*)d_in[9];
    float* out = (float*)d_out;

    char* ws = (char*)d_ws;
    int* cnt               = (int*)(ws);                                  // 1.2 MB
    int* cursor            = (int*)(ws + ((size_t)2  << 20));             // 1.2 MB
    int* rowstart          = (int*)(ws + ((size_t)4  << 20));             // 1.2 MB
    int* blocksum          = (int*)(ws + ((size_t)55 << 17));             // 5.5 MB, tiny
    unsigned short* WcatT  = (unsigned short*)(ws + ((size_t)6  << 20));  // 192 KB
    unsigned short* Wcat2T = (unsigned short*)(ws + ((size_t)13 << 19));  // 6.5 MB, 32 KB
    int* adj               = (int*)(ws + ((size_t)8  << 20));             // 7.2 MB
    unsigned short* aggb   = (unsigned short*)(ws + ((size_t)16 << 20));  // 76.8 MB
    unsigned short* hWlb   = (unsigned short*)(ws + ((size_t)96 << 20));  // 12.8 MB

    hipMemsetAsync(cnt, 0, 3 * N_NODES * sizeof(int), stream);
    hipMemsetAsync(cursor, 0, 3 * N_NODES * sizeof(int), stream);

    dim3 ge((N_EDGES + 255) / 256, 3);
    count_kernel<<<ge, 256, 0, stream>>>(ei0, ei1, ei2, cnt);
    scan1_kernel<<<dim3(NCHUNK, 3), 1024, 0, stream>>>(cnt, rowstart, blocksum);
    scan2_kernel<<<1, 128, 0, stream>>>(blocksum);
    scan3_kernel<<<dim3(392, 3), 256, 0, stream>>>(rowstart, blocksum);
    fill_kernel<<<ge, 256, 0, stream>>>(ei0, ei1, ei2, rowstart, cursor, adj);
    wprep_kernel<<<448, 256, 0, stream>>>(Wl, Wr, Wl_f, Wr_f, WcatT, Wcat2T);

    const int GATHER_BLOCKS = (N_NODES + 3) / 4;  // 4 waves/block, 1 node/wave
    for (int r = 0; r < 3; r++)
        gather128_kernel<<<GATHER_BLOCKS, 256, 0, stream>>>(
            x, adj + (size_t)r * N_EDGES, rowstart + r * N_NODES, cnt + r * N_NODES,
            aggb + (size_t)r * NROWS2 * 128);

    mega_kernel<<<(N_NODES + 63) / 64, 256, 0, stream>>>(
        aggb, x, WcatT, bl, Wcat2T, bl_f, hWlb, out);

    gather64_kernel<<<GATHER_BLOCKS, 256, 0, stream>>>(hWlb, adj, rowstart, cnt, out);
}

// Round 4
// 554.099 us; speedup vs baseline: 5.3069x; 1.2777x over previous
//
#include <hip/hip_runtime.h>

#define N_NODES 100000
#define N_EDGES 600000
#define NCHUNK 98            // ceil(100000/1024)
#define NROWS2 100032        // N_NODES rounded up to 64
#define LDS_STRIDE 136       // ushorts per row: 128 + 8 pad

typedef __attribute__((ext_vector_type(8))) short short8;
typedef __attribute__((ext_vector_type(4))) float f32x4;
typedef __attribute__((ext_vector_type(2))) unsigned short ushort2v;
typedef __attribute__((ext_vector_type(8))) unsigned short ushort8v;

__device__ __forceinline__ unsigned short f2b(float f) {   // fp32 -> bf16 RNE
    unsigned u = __builtin_bit_cast(unsigned, f);
    return (unsigned short)((u + 0x7fffu + ((u >> 16) & 1u)) >> 16);
}
__device__ __forceinline__ float b2f(unsigned short b) {
    return __builtin_bit_cast(float, (unsigned)b << 16);
}

// ---------------------------------------------------------------------------
__global__ void count_kernel(const int* __restrict__ e0, const int* __restrict__ e1,
                             const int* __restrict__ e2, int* __restrict__ cnt) {
    int e = blockIdx.x * blockDim.x + threadIdx.x;
    if (e >= N_EDGES) return;
    int r = blockIdx.y;
    const int* ei = (r == 0) ? e0 : (r == 1 ? e1 : e2);
    atomicAdd(&cnt[r * N_NODES + ei[N_EDGES + e]], 1);
}

// ---------------------------------------------------------------------------
__global__ __launch_bounds__(1024) void scan1_kernel(const int* __restrict__ cnt,
                                                     int* __restrict__ rowstart,
                                                     int* __restrict__ blocksum) {
    int r = blockIdx.y;
    int tid = threadIdx.x, lane = tid & 63, wid = tid >> 6;
    int i = blockIdx.x * 1024 + tid;
    __shared__ int wsum[16];
    int v = (i < N_NODES) ? cnt[r * N_NODES + i] : 0;
    int incl = v;
#pragma unroll
    for (int off = 1; off < 64; off <<= 1) {
        int t = __shfl_up(incl, off);
        if (lane >= off) incl += t;
    }
    if (lane == 63) wsum[wid] = incl;
    __syncthreads();
    if (wid == 0) {
        int wv = (lane < 16) ? wsum[lane] : 0;
#pragma unroll
        for (int off = 1; off < 16; off <<= 1) {
            int t = __shfl_up(wv, off);
            if (lane >= off) wv += t;
        }
        if (lane < 16) wsum[lane] = wv;
    }
    __syncthreads();
    int woff = (wid > 0) ? wsum[wid - 1] : 0;
    if (i < N_NODES) rowstart[r * N_NODES + i] = woff + incl - v;
    if (tid == 0) blocksum[r * NCHUNK + blockIdx.x] = wsum[15];
}

__global__ __launch_bounds__(128) void scan2_kernel(int* __restrict__ blocksum) {
    __shared__ int s[3 * NCHUNK];
    int tid = threadIdx.x;
    for (int i = tid; i < 3 * NCHUNK; i += 128) s[i] = blocksum[i];
    __syncthreads();
    if (tid < 3) {
        int run = 0;
        for (int j = 0; j < NCHUNK; j++) { int t = s[tid * NCHUNK + j]; s[tid * NCHUNK + j] = run; run += t; }
    }
    __syncthreads();
    for (int i = tid; i < 3 * NCHUNK; i += 128) blocksum[i] = s[i];
}

__global__ void scan3_kernel(int* __restrict__ rowstart, const int* __restrict__ blocksum) {
    int r = blockIdx.y;
    int i = blockIdx.x * 256 + threadIdx.x;
    if (i < N_NODES) rowstart[r * N_NODES + i] += blocksum[r * NCHUNK + (i >> 10)];
}

// ---------------------------------------------------------------------------
__global__ void fill_kernel(const int* __restrict__ e0, const int* __restrict__ e1,
                            const int* __restrict__ e2, const int* __restrict__ rowstart,
                            int* __restrict__ cursor, int* __restrict__ adj) {
    int e = blockIdx.x * blockDim.x + threadIdx.x;
    if (e >= N_EDGES) return;
    int r = blockIdx.y;
    const int* ei = (r == 0) ? e0 : (r == 1 ? e1 : e2);
    int src = ei[e], dst = ei[N_EDGES + e];
    int pos = atomicAdd(&cursor[r * N_NODES + dst], 1);
    adj[(size_t)r * N_EDGES + rowstart[r * N_NODES + dst] + pos] = src;
}

// ---------------------------------------------------------------------------
// x (fp32) -> xb (bf16), 8 elems/thread. Grid exactly N_NODES*128/8/256 blocks.
__global__ void xcast_kernel(const float* __restrict__ x, unsigned short* __restrict__ xb) {
    int idx = blockIdx.x * 256 + threadIdx.x;
    const float4* p = (const float4*)x + (size_t)idx * 2;
    float4 a = p[0], b = p[1];
    ushort8v o;
    o[0] = f2b(a.x); o[1] = f2b(a.y); o[2] = f2b(a.z); o[3] = f2b(a.w);
    o[4] = f2b(b.x); o[5] = f2b(b.y); o[6] = f2b(b.z); o[7] = f2b(b.w);
    *(ushort8v*)(xb + (size_t)idx * 8) = o;
}

// ---------------------------------------------------------------------------
// Pre-swizzle weights into MFMA B-fragment order so kernel B-loads are
// coalesced lane*16B bursts.
// Layer1 frag idx: (((r*4+w)*8+s)*2+t)*512 + lane*8 + j
//   value = (k<128 ? Wl[r][k][n] : Wr[r][k-128][n]), k=s*32+quad*8+j, n=w*32+t*16+l16
// Layer2 frag idx: ((w*4+s)*2+t)*512 + lane*8 + j
//   value = (n<64 ? Wl_f[k][n] : Wr_f[k][n-64]), k=s*32+quad*8+j, n=w*32+t*16+l16
__global__ void wprep_kernel(const float* __restrict__ Wl, const float* __restrict__ Wr,
                             const float* __restrict__ Wl_f, const float* __restrict__ Wr_f,
                             unsigned short* __restrict__ Wfrag, unsigned short* __restrict__ Wfrag2) {
    int idx = blockIdx.x * 256 + threadIdx.x;      // 448 blocks = 114688 threads
    int j = idx & 7, lane = (idx >> 3) & 63;
    int quad = lane >> 4, l16 = lane & 15;
    if (idx < 98304) {
        int t = (idx >> 9) & 1, s = (idx >> 10) & 7, w = (idx >> 13) & 3, r = idx >> 15;
        int k = s * 32 + quad * 8 + j;
        int n = w * 32 + t * 16 + l16;
        float v = (k < 128) ? Wl[((size_t)r * 128 + k) * 128 + n]
                            : Wr[((size_t)r * 128 + (k - 128)) * 128 + n];
        Wfrag[idx] = f2b(v);
    } else {
        int i2 = idx - 98304;
        if (i2 < 16384) {
            int t = (i2 >> 9) & 1, s = (i2 >> 10) & 3, w = (i2 >> 12) & 3;
            int k = s * 32 + quad * 8 + j;
            int n = w * 32 + t * 16 + l16;
            float v = (n < 64) ? Wl_f[(size_t)k * 64 + n] : Wr_f[(size_t)k * 64 + (n - 64)];
            Wfrag2[i2] = f2b(v);
        }
    }
}

// ---------------------------------------------------------------------------
// Gather-mean from bf16 rows (256 B/row): one wave/node, ushort2 per lane.
__global__ void gather128_kernel(const unsigned short* __restrict__ xb, const int* __restrict__ adj,
                                 const int* __restrict__ rowstart, const int* __restrict__ cnt,
                                 unsigned short* __restrict__ aggb) {
    int node = (blockIdx.x * blockDim.x + threadIdx.x) >> 6;
    int lane = threadIdx.x & 63;
    if (node >= N_NODES) return;
    int start = rowstart[node];
    int deg = cnt[node];
    float ax = 0.f, ay = 0.f;
    int j = 0;
    for (; j + 4 <= deg; j += 4) {
        int s0 = adj[start + j], s1 = adj[start + j + 1];
        int s2 = adj[start + j + 2], s3 = adj[start + j + 3];
        ushort2v v0 = *(const ushort2v*)(xb + (size_t)s0 * 128 + lane * 2);
        ushort2v v1 = *(const ushort2v*)(xb + (size_t)s1 * 128 + lane * 2);
        ushort2v v2 = *(const ushort2v*)(xb + (size_t)s2 * 128 + lane * 2);
        ushort2v v3 = *(const ushort2v*)(xb + (size_t)s3 * 128 + lane * 2);
        ax += b2f(v0.x) + b2f(v1.x) + b2f(v2.x) + b2f(v3.x);
        ay += b2f(v0.y) + b2f(v1.y) + b2f(v2.y) + b2f(v3.y);
    }
    for (; j < deg; j++) {
        int s = adj[start + j];
        ushort2v v = *(const ushort2v*)(xb + (size_t)s * 128 + lane * 2);
        ax += b2f(v.x); ay += b2f(v.y);
    }
    float inv = 1.0f / fmaxf((float)deg, 1.0f);
    ushort2v o; o.x = f2b(ax * inv); o.y = f2b(ay * inv);
    *(ushort2v*)(aggb + (size_t)node * 128 + lane * 2) = o;
}

// ---------------------------------------------------------------------------
// Layer-1 for one relation: hb (+)= relu([agg|x](K=256) @ W + bl) / 3  (bf16 RMW)
// 64 rows x 128 cols per block; wave w owns cols [w*32, w*32+32).
__global__ __launch_bounds__(256, 4) void layer1_kernel(
    const unsigned short* __restrict__ aggb, const unsigned short* __restrict__ xb,
    const unsigned short* __restrict__ Wfrag, const float* __restrict__ bl,
    unsigned short* __restrict__ hb, int first) {
    __shared__ unsigned short s_a[64 * LDS_STRIDE];
    __shared__ unsigned short s_x[64 * LDS_STRIDE];
    int tid = threadIdx.x, wave = tid >> 6, lane = tid & 63;
    int quad = lane >> 4, l16 = lane & 15;
    int rowbase = blockIdx.x * 64;

#pragma unroll
    for (int it = 0; it < 4; it++) {
        int idx = tid + it * 256;
        int row = idx >> 4, c = idx & 15;
        int grow = rowbase + row;
        short8 xv = {0, 0, 0, 0, 0, 0, 0, 0};
        if (grow < N_NODES) xv = *(const short8*)(xb + (size_t)grow * 128 + c * 8);
        *(short8*)&s_x[row * LDS_STRIDE + c * 8] = xv;
        short8 av = *(const short8*)(aggb + (size_t)(rowbase + row) * 128 + c * 8);
        *(short8*)&s_a[row * LDS_STRIDE + c * 8] = av;
    }
    __syncthreads();

    f32x4 acc[4][2];
#pragma unroll
    for (int g = 0; g < 4; g++) { acc[g][0] = (f32x4){0.f,0.f,0.f,0.f}; acc[g][1] = (f32x4){0.f,0.f,0.f,0.f}; }

    const unsigned short* W = Wfrag + wave * 8192;
#pragma unroll
    for (int s = 0; s < 8; s++) {
        short8 bf0 = *(const short8*)(W + s * 1024 + lane * 8);         // coalesced 1KB
        short8 bf1 = *(const short8*)(W + s * 1024 + 512 + lane * 8);
        const unsigned short* src = (s < 4) ? s_a : s_x;
        int ko = (s & 3) * 32 + quad * 8;
#pragma unroll
        for (int g = 0; g < 4; g++) {
            short8 af = *(const short8*)&src[(g * 16 + l16) * LDS_STRIDE + ko];
            acc[g][0] = __builtin_amdgcn_mfma_f32_16x16x32_bf16(af, bf0, acc[g][0], 0, 0, 0);
            acc[g][1] = __builtin_amdgcn_mfma_f32_16x16x32_bf16(af, bf1, acc[g][1], 0, 0, 0);
        }
    }

    float b0 = bl[wave * 32 + l16];
    float b1 = bl[wave * 32 + 16 + l16];
#pragma unroll
    for (int g = 0; g < 4; g++)
#pragma unroll
        for (int t = 0; t < 2; t++) {
            float bb = t ? b1 : b0;
            int col = wave * 32 + t * 16 + l16;
#pragma unroll
            for (int q = 0; q < 4; q++) {
                int row = rowbase + g * 16 + quad * 4 + q;
                if (row < N_NODES) {
                    float v = fmaxf(acc[g][t][q] + bb, 0.f) * (1.0f / 3.0f);
                    size_t o = (size_t)row * 128 + col;
                    if (!first) v += b2f(hb[o]);
                    hb[o] = f2b(v);
                }
            }
        }
}

// ---------------------------------------------------------------------------
// Layer-2: [hWl|hWr] = h @ Wf2 (K=128); hWl -> bf16 buffer, out = hWr + bl_f.
__global__ __launch_bounds__(256, 4) void layer2_kernel(
    const unsigned short* __restrict__ hb, const unsigned short* __restrict__ Wfrag2,
    const float* __restrict__ bl_f, unsigned short* __restrict__ hWlb,
    float* __restrict__ out) {
    __shared__ unsigned short s_h[64 * LDS_STRIDE];
    int tid = threadIdx.x, wave = tid >> 6, lane = tid & 63;
    int quad = lane >> 4, l16 = lane & 15;
    int rowbase = blockIdx.x * 64;

#pragma unroll
    for (int it = 0; it < 4; it++) {
        int idx = tid + it * 256;
        int row = idx >> 4, c = idx & 15;
        int grow = rowbase + row;
        short8 hv = {0, 0, 0, 0, 0, 0, 0, 0};
        if (grow < N_NODES) hv = *(const short8*)(hb + (size_t)grow * 128 + c * 8);
        *(short8*)&s_h[row * LDS_STRIDE + c * 8] = hv;
    }
    __syncthreads();

    f32x4 acc[4][2];
#pragma unroll
    for (int g = 0; g < 4; g++) { acc[g][0] = (f32x4){0.f,0.f,0.f,0.f}; acc[g][1] = (f32x4){0.f,0.f,0.f,0.f}; }

    const unsigned short* W = Wfrag2 + wave * 4096;
#pragma unroll
    for (int s = 0; s < 4; s++) {
        short8 bf0 = *(const short8*)(W + s * 1024 + lane * 8);
        short8 bf1 = *(const short8*)(W + s * 1024 + 512 + lane * 8);
        int ko = s * 32 + quad * 8;
#pragma unroll
        for (int g = 0; g < 4; g++) {
            short8 af = *(const short8*)&s_h[(g * 16 + l16) * LDS_STRIDE + ko];
            acc[g][0] = __builtin_amdgcn_mfma_f32_16x16x32_bf16(af, bf0, acc[g][0], 0, 0, 0);
            acc[g][1] = __builtin_amdgcn_mfma_f32_16x16x32_bf16(af, bf1, acc[g][1], 0, 0, 0);
        }
    }

#pragma unroll
    for (int g = 0; g < 4; g++)
#pragma unroll
        for (int t = 0; t < 2; t++) {
            int col = wave * 32 + t * 16 + l16;
#pragma unroll
            for (int q = 0; q < 4; q++) {
                int row = rowbase + g * 16 + quad * 4 + q;
                if (row < N_NODES) {
                    if (col < 64) hWlb[(size_t)row * 64 + col] = f2b(acc[g][t][q]);
                    else out[(size_t)row * 64 + (col - 64)] = acc[g][t][q] + bl_f[col - 64];
                }
            }
        }
}

// ---------------------------------------------------------------------------
// Gather-mean of hWl (bf16, 64 ch) + add into out (holds hWr + bl_f).
__global__ void gather64_kernel(const unsigned short* __restrict__ hWlb, const int* __restrict__ adj,
                                const int* __restrict__ rowstart, const int* __restrict__ cnt,
                                float* __restrict__ out) {
    int node = (blockIdx.x * blockDim.x + threadIdx.x) >> 6;
    int lane = threadIdx.x & 63;
    if (node >= N_NODES) return;
    int start = rowstart[node];
    int deg = cnt[node];
    float a = 0.f;
    int j = 0;
    for (; j + 4 <= deg; j += 4) {
        int s0 = adj[start + j], s1 = adj[start + j + 1];
        int s2 = adj[start + j + 2], s3 = adj[start + j + 3];
        a += b2f(hWlb[(size_t)s0 * 64 + lane]) + b2f(hWlb[(size_t)s1 * 64 + lane])
           + b2f(hWlb[(size_t)s2 * 64 + lane]) + b2f(hWlb[(size_t)s3 * 64 + lane]);
    }
    for (; j < deg; j++) a += b2f(hWlb[(size_t)adj[start + j] * 64 + lane]);
    out[(size_t)node * 64 + lane] += a / fmaxf((float)deg, 1.0f);
}

// ---------------------------------------------------------------------------
extern "C" void kernel_launch(void* const* d_in, const int* in_sizes, int n_in,
                              void* d_out, int out_size, void* d_ws, size_t ws_size,
                              hipStream_t stream) {
    const float* x    = (const float*)d_in[0];
    const float* Wl   = (const float*)d_in[1];
    const float* bl   = (const float*)d_in[2];
    const float* Wr   = (const float*)d_in[3];
    const float* Wl_f = (const float*)d_in[4];
    const float* bl_f = (const float*)d_in[5];
    const float* Wr_f = (const float*)d_in[6];
    const int* ei0 = (const int*)d_in[7];
    const int* ei1 = (const int*)d_in[8];
    const int* ei2 = (const int*)d_in[9];
    float* out = (float*)d_out;

    // workspace layout (MB offsets), total ~107 MB
    char* ws = (char*)d_ws;
    int* cnt               = (int*)(ws);                                   // 1.2 MB
    int* cursor            = (int*)(ws + ((size_t)2  << 20));              // 1.2 MB
    int* rowstart          = (int*)(ws + ((size_t)4  << 20));              // 1.2 MB
    int* blocksum          = (int*)(ws + ((size_t)6  << 20));              // 1.2 KB
    unsigned short* Wfrag  = (unsigned short*)(ws + ((size_t)7  << 20));   // 192 KB
    unsigned short* Wfrag2 = (unsigned short*)(ws + ((size_t)15 << 19));   // 7.5MB, 32 KB
    int* adj               = (int*)(ws + ((size_t)8  << 20));              // 7.2 MB
    unsigned short* xb     = (unsigned short*)(ws + ((size_t)16 << 20));   // 25.6 MB
    unsigned short* aggb   = (unsigned short*)(ws + ((size_t)42 << 20));   // 25.6 MB
    unsigned short* hb     = (unsigned short*)(ws + ((size_t)68 << 20));   // 25.6 MB
    unsigned short* hWlb   = (unsigned short*)(ws + ((size_t)94 << 20));   // 12.8 MB

    hipMemsetAsync(cnt, 0, 3 * N_NODES * sizeof(int), stream);
    hipMemsetAsync(cursor, 0, 3 * N_NODES * sizeof(int), stream);

    dim3 ge((N_EDGES + 255) / 256, 3);
    count_kernel<<<ge, 256, 0, stream>>>(ei0, ei1, ei2, cnt);
    scan1_kernel<<<dim3(NCHUNK, 3), 1024, 0, stream>>>(cnt, rowstart, blocksum);
    scan2_kernel<<<1, 128, 0, stream>>>(blocksum);
    scan3_kernel<<<dim3(392, 3), 256, 0, stream>>>(rowstart, blocksum);
    fill_kernel<<<ge, 256, 0, stream>>>(ei0, ei1, ei2, rowstart, cursor, adj);
    wprep_kernel<<<448, 256, 0, stream>>>(Wl, Wr, Wl_f, Wr_f, Wfrag, Wfrag2);
    xcast_kernel<<<(N_NODES * 128 / 8) / 256, 256, 0, stream>>>(x, xb);

    const int GATHER_BLOCKS = (N_NODES + 3) / 4;   // one wave per node
    const int TILE_BLOCKS = (N_NODES + 63) / 64;   // 1563
    for (int r = 0; r < 3; r++) {
        gather128_kernel<<<GATHER_BLOCKS, 256, 0, stream>>>(
            xb, adj + (size_t)r * N_EDGES, rowstart + r * N_NODES, cnt + r * N_NODES, aggb);
        layer1_kernel<<<TILE_BLOCKS, 256, 0, stream>>>(
            aggb, xb, Wfrag + (size_t)r * 32768, bl + r * 128, hb, r == 0 ? 1 : 0);
    }

    layer2_kernel<<<TILE_BLOCKS, 256, 0, stream>>>(hb, Wfrag2, bl_f, hWlb, out);
    gather64_kernel<<<GATHER_BLOCKS, 256, 0, stream>>>(hWlb, adj, rowstart, cnt, out);
}